// Round 6
// baseline (972.538 us; speedup 1.0000x reference)
//
#include <hip/hip_runtime.h>
#include <math.h>

#define B_ 32
#define INLEN 10
#define LIN_ 16384
#define NPOLY 12
#define MM 6
#define CH 20
#define NB 4
#define RECEPT 25
#define L0 16434      // length after first conv
#define TTILE 216     // outputs per tile (multiple of 6)
#define NW 37         // TTILE/6 + 1 windows
#define XS_LEN 228    // TTILE + 12 halo
#define XS_PAD 229    // odd stride -> bank-conflict-free strided reads
#define GS_LEN 218    // TTILE + 2 gelu positions
#define LXS_PAD 121   // odd stride (121 mod 32 = 25, coprime with 32)
#define CCHUNK 5      // ci-chunk in stages B/D: caps live x-window regs (R5 spill fix)
#define COH 10        // output channels per 256-thread half (CH/2)

__device__ __forceinline__ float gelu_exact(float x) {
    return 0.5f * x * (1.0f + erff(x * 0.70710678118654752440f));
}

// ---------------- first conv: (B,10,16384) wrap-padded -> (B,20,16434) ----------------
__global__ void k_first(const float* __restrict__ in, const float* __restrict__ wf,
                        float* __restrict__ out) {
    int t = blockIdx.x * blockDim.x + threadIdx.x;
    int b = blockIdx.y;
    if (t >= L0) return;
    const float* inb = in + (size_t)b * INLEN * LIN_;
    float xw[INLEN][3];
#pragma unroll
    for (int ci = 0; ci < INLEN; ++ci) {
#pragma unroll
        for (int k = 0; k < 3; ++k) {
            int idx = t + k - RECEPT;
            idx = (idx < 0) ? idx + LIN_ : (idx >= LIN_ ? idx - LIN_ : idx);
            xw[ci][k] = inb[ci * LIN_ + idx];
        }
    }
    float* outb = out + (size_t)b * CH * L0;
#pragma unroll
    for (int co = 0; co < CH; ++co) {
        float acc = 0.f;
#pragma unroll
        for (int ci = 0; ci < INLEN; ++ci)
#pragma unroll
            for (int k = 0; k < 3; ++k)
                acc = fmaf(xw[ci][k], wf[(co * INLEN + ci) * 3 + k], acc);
        outb[(size_t)co * L0 + t] = acc;
    }
}

// ---------------- fused block: residual conv path + Legendre multiwavelet path ----------------
// R6: 512 threads/block, same TTILE and LDS (39.4 KB -> still 4 blocks/CU) but 8 waves/block
// -> 32 waves/CU theoretical (was 16). The two 256-thread halves split the 20 output
// channels of stages B and D (10 each); per-thread FMA and live registers halve.
// R5 lessons kept: ci chunked (CCHUNK=5, `#pragma unroll 1`) so LICM can't rebuild the
// 60-reg window; no aggressive occupancy hints (RA spills when over-squeezed).
__global__ __launch_bounds__(512, 2)
void k_block(const float* __restrict__ x, float* __restrict__ xn,
             const float* __restrict__ wA, const float* __restrict__ wB,
             const float* __restrict__ linm, const float* __restrict__ fd,
             const float* __restrict__ fr, int l) {
    const int lout = l - 12;
    const int tid  = threadIdx.x;          // 0..511
    const int t    = tid & 255;            // position within half
    const int half = tid >> 8;             // 0: co 0..9, 1: co 10..19
    const int cob  = half * COH;           // first output channel of this half
    const int t0   = blockIdx.x * TTILE;   // multiple of 6
    const int b    = blockIdx.y;

    __shared__ float xs[CH][XS_PAD];       // x tile; after C1+B, reused as gs tile
    __shared__ float lxs[NW][LXS_PAD];     // Legendre coeffs, layout [wl][u], u = m*20+c
    __shared__ float lm_s[CH * MM * MM];   // lin_m[i] : [g][o][i]
    __shared__ float fr_s[MM * NPOLY];     // filt_r

    const float* xb = x + (size_t)b * CH * l;

    for (int i = tid; i < CH * MM * MM; i += 512) lm_s[i] = linm[i];
    for (int i = tid; i < MM * NPOLY; i += 512)   fr_s[i] = fr[i];

    // stage A: load x tile (zero-fill past end; those outputs are masked)
    for (int i = tid; i < CH * XS_LEN; i += 512) {
        int c = i / XS_LEN, p = i - c * XS_LEN;
        int gp = t0 + p;
        xs[c][p] = (gp < l) ? xb[(size_t)c * l + gp] : 0.f;
    }
    __syncthreads();

    // stage C1: Legendre decomposition per (window, channel): Lx[m] = sum_k x[6wl+k]*fd[m][k]/2
    for (int item = tid; item < NW * CH; item += 512) {
        int wl = item / CH, c = item - wl * CH;
        float xv[NPOLY];
#pragma unroll
        for (int k = 0; k < NPOLY; ++k) xv[k] = xs[c][6 * wl + k];
#pragma unroll
        for (int m = 0; m < MM; ++m) {
            float acc = 0.f;
#pragma unroll
            for (int k = 0; k < NPOLY; ++k)
                acc = fmaf(xv[k], fd[m * NPOLY + k], acc);
            lxs[wl][m * CH + c] = acc * 0.5f;
        }
    }

    // stage B: this half computes gelu(conv_a(x)) for its 10 output channels
    float gv[COH];
    if (t < GS_LEN) {
#pragma unroll
        for (int co = 0; co < COH; ++co) gv[co] = 0.f;
#pragma unroll 1
        for (int cig = 0; cig < CH; cig += CCHUNK) {
            float xw[CCHUNK][3];
#pragma unroll
            for (int j = 0; j < CCHUNK; ++j) {
                xw[j][0] = xs[cig + j][t + 4];
                xw[j][1] = xs[cig + j][t + 5];
                xw[j][2] = xs[cig + j][t + 6];
            }
#pragma unroll
            for (int co = 0; co < COH; ++co) {
                float acc = gv[co];
#pragma unroll
                for (int j = 0; j < CCHUNK; ++j)
#pragma unroll
                    for (int k = 0; k < 3; ++k)
                        acc = fmaf(xw[j][k], wA[((cob + co) * CH + cig + j) * 3 + k], acc);
                gv[co] = acc;
            }
        }
#pragma unroll
        for (int co = 0; co < COH; ++co) gv[co] = gelu_exact(gv[co]);
    }
    __syncthreads();   // all reads of xs (C1 + B) complete block-wide

    // write g into the dead xs region (each half writes its 10 rows)
    if (t < GS_LEN) {
#pragma unroll
        for (int co = 0; co < COH; ++co) xs[cob + co][t] = gv[co];
    }

    // stage C2: grouped mode mixing on flattened mode-major index u = m*20+c,
    // groups are 6-consecutive u's (block-diagonal -> safe in place)
    for (int item = tid; item < NW * CH; item += 512) {
        int wl = item / CH, g = item - wl * CH;
        float iv[MM], ov[MM];
#pragma unroll
        for (int i = 0; i < MM; ++i) iv[i] = lxs[wl][g * MM + i];
#pragma unroll
        for (int o = 0; o < MM; ++o) {
            float acc = 0.f;
#pragma unroll
            for (int i = 0; i < MM; ++i)
                acc = fmaf(iv[i], lm_s[(g * MM + o) * MM + i], acc);
            ov[o] = acc;
        }
#pragma unroll
        for (int o = 0; o < MM; ++o) lxs[wl][g * MM + o] = ov[o];
    }
    __syncthreads();

    // stage D: out[t'] = gelu( rec[t'+6] + conv_b(g)[t'+4] ) for this half's 10 channels
    if (t < TTILE && t0 + t < lout) {
        const int tp = t;
        float acc[COH];
#pragma unroll
        for (int co = 0; co < COH; ++co) acc[co] = 0.f;
#pragma unroll 1
        for (int cig = 0; cig < CH; cig += CCHUNK) {
            float aw[CCHUNK][3];
#pragma unroll
            for (int j = 0; j < CCHUNK; ++j) {
                aw[j][0] = xs[cig + j][tp];
                aw[j][1] = xs[cig + j][tp + 1];
                aw[j][2] = xs[cig + j][tp + 2];
            }
#pragma unroll
            for (int co = 0; co < COH; ++co) {
                float a = acc[co];
#pragma unroll
                for (int j = 0; j < CCHUNK; ++j)
#pragma unroll
                    for (int k = 0; k < 3; ++k)
                        a = fmaf(aw[j][k], wB[((cob + co) * CH + cig + j) * 3 + k], a);
                acc[co] = a;
            }
        }
        const int r1  = tp % 6;        // (t0+tp+6) % 6
        const int wl1 = tp / 6 + 1;    // local window (t'+6)/6, <= 36 < NW
        float frA[MM], frB[MM];
#pragma unroll
        for (int m = 0; m < MM; ++m) {
            frA[m] = fr_s[m * NPOLY + r1];
            frB[m] = fr_s[m * NPOLY + r1 + 6];
        }
        float* xnb = xn + (size_t)b * CH * lout;
#pragma unroll
        for (int co = 0; co < COH; ++co) {
            float rec = 0.f;
#pragma unroll
            for (int m = 0; m < MM; ++m) {
                rec = fmaf(lxs[wl1][m * CH + cob + co], frA[m], rec);
                rec = fmaf(lxs[wl1 - 1][m * CH + cob + co], frB[m], rec);
            }
            xnb[(size_t)(cob + co) * lout + t0 + tp] = gelu_exact(acc[co] + rec);
        }
    }
}

// ---------------- final: gelu(20->128) -> 128->1, slice to 16384 ----------------
__global__ void k_final(const float* __restrict__ x, const float* __restrict__ w11,
                        const float* __restrict__ wout, float* __restrict__ out) {
    int t = blockIdx.x * blockDim.x + threadIdx.x;
    int b = blockIdx.y;
    if (t >= LIN_) return;
    const int l4 = L0 - NB * 12;   // 16386
    const float* xb = x + (size_t)b * CH * l4;
    float xv[CH];
#pragma unroll
    for (int c = 0; c < CH; ++c) xv[c] = xb[(size_t)c * l4 + t];
    float acc0 = 0.f, acc1 = 0.f, acc2 = 0.f, acc3 = 0.f;
    for (int h = 0; h < 128; h += 4) {
        float hv0 = 0.f, hv1 = 0.f, hv2 = 0.f, hv3 = 0.f;
#pragma unroll
        for (int c = 0; c < CH; ++c) {
            hv0 = fmaf(xv[c], w11[(h + 0) * CH + c], hv0);
            hv1 = fmaf(xv[c], w11[(h + 1) * CH + c], hv1);
            hv2 = fmaf(xv[c], w11[(h + 2) * CH + c], hv2);
            hv3 = fmaf(xv[c], w11[(h + 3) * CH + c], hv3);
        }
        acc0 = fmaf(gelu_exact(hv0), wout[h + 0], acc0);
        acc1 = fmaf(gelu_exact(hv1), wout[h + 1], acc1);
        acc2 = fmaf(gelu_exact(hv2), wout[h + 2], acc2);
        acc3 = fmaf(gelu_exact(hv3), wout[h + 3], acc3);
    }
    out[(size_t)b * LIN_ + t] = (acc0 + acc1) + (acc2 + acc3);
}

extern "C" void kernel_launch(void* const* d_in, const int* in_sizes, int n_in,
                              void* d_out, int out_size, void* d_ws, size_t ws_size,
                              hipStream_t stream) {
    const float* input   = (const float*)d_in[0];
    const float* w_first = (const float*)d_in[1];
    const float* conv_a  = (const float*)d_in[2];
    const float* conv_b  = (const float*)d_in[3];
    const float* lin_m   = (const float*)d_in[4];
    const float* w11     = (const float*)d_in[5];
    const float* w_out   = (const float*)d_in[6];
    const float* filt_d  = (const float*)d_in[7];
    const float* filt_r  = (const float*)d_in[8];
    float* out = (float*)d_out;

    const size_t bufElems = (size_t)B_ * CH * L0;   // 10,517,760 floats = 42.07 MB
    float* xA = (float*)d_ws;
    float* xB = xA + bufElems;

    {
        dim3 grid((L0 + 255) / 256, B_);
        k_first<<<grid, 256, 0, stream>>>(input, w_first, xA);
    }

    int l = L0;
    float* cur = xA;
    float* nxt = xB;
    for (int i = 0; i < NB; ++i) {
        int lout  = l - 12;
        int tiles = (lout + TTILE - 1) / TTILE;
        dim3 grid(tiles, B_);
        k_block<<<grid, 512, 0, stream>>>(cur, nxt,
                                          conv_a + i * CH * CH * 3,
                                          conv_b + i * CH * CH * 3,
                                          lin_m + i * CH * MM * MM,
                                          filt_d, filt_r, l);
        float* tswap = cur; cur = nxt; nxt = tswap;
        l = lout;
    }

    {
        dim3 grid((LIN_ + 255) / 256, B_);
        k_final<<<grid, 256, 0, stream>>>(cur, w11, w_out, out);
    }
}

// Round 7
// 518.281 us; speedup vs baseline: 1.8765x; 1.8765x over previous
//
#include <hip/hip_runtime.h>
#include <math.h>

#define B_ 32
#define INLEN 10
#define LIN_ 16384
#define NPOLY 12
#define MM 6
#define CH 20
#define NB 4
#define RECEPT 25
#define L0 16434      // length after first conv
#define TTILE 216     // outputs per tile (multiple of 6)
#define NW 37         // TTILE/6 + 1 windows
#define XS_LEN 228    // TTILE + 12 halo
#define XS_PAD 229    // odd stride -> bank-conflict-free strided reads
#define GS_LEN 218    // TTILE + 2 gelu positions
#define LXS_PAD 121   // odd stride (121 mod 32 = 25, coprime with 32)
#define CCHUNK 5      // ci-chunk in stages B/D: caps live x-window regs (R5 spill fix)
#define COH 10        // output channels per 256-thread half (CH/2)

__device__ __forceinline__ float gelu_exact(float x) {
    return 0.5f * x * (1.0f + erff(x * 0.70710678118654752440f));
}

// ---------------- first conv: (B,10,16384) wrap-padded -> (B,20,16434) ----------------
__global__ void k_first(const float* __restrict__ in, const float* __restrict__ wf,
                        float* __restrict__ out) {
    int t = blockIdx.x * blockDim.x + threadIdx.x;
    int b = blockIdx.y;
    if (t >= L0) return;
    const float* inb = in + (size_t)b * INLEN * LIN_;
    float xw[INLEN][3];
#pragma unroll
    for (int ci = 0; ci < INLEN; ++ci) {
#pragma unroll
        for (int k = 0; k < 3; ++k) {
            int idx = t + k - RECEPT;
            idx = (idx < 0) ? idx + LIN_ : (idx >= LIN_ ? idx - LIN_ : idx);
            xw[ci][k] = inb[ci * LIN_ + idx];
        }
    }
    float* outb = out + (size_t)b * CH * L0;
#pragma unroll
    for (int co = 0; co < CH; ++co) {
        float acc = 0.f;
#pragma unroll
        for (int ci = 0; ci < INLEN; ++ci)
#pragma unroll
            for (int k = 0; k < 3; ++k)
                acc = fmaf(xw[ci][k], wf[(co * INLEN + ci) * 3 + k], acc);
        outb[(size_t)co * L0 + t] = acc;
    }
}

// ---------------- fused block: residual conv path + Legendre multiwavelet path ----------------
// R7: R6's 512-thread/half-split structure + WAVE-UNIFORMITY FIX. R6 regression root cause:
// cob = (tid>>8)*10 is per-thread in the compiler's eyes, so all ~2400 weight reads in
// stages B/D became per-lane global_load_dword (VMEM flood, 2x issue count) instead of
// s_load broadcasts. cob IS uniform within a wave -> assert it with readfirstlane and
// hoist SGPR base pointers; weight indices are then SGPR-base + literal -> s_load again.
// R5 lessons kept: ci chunked (CCHUNK=5, unroll 1) against LICM window rebuild; LDS 39.4 KB
// -> 4 blocks/CU x 8 waves = 32 waves/CU theoretical.
__global__ __launch_bounds__(512, 2)
void k_block(const float* __restrict__ x, float* __restrict__ xn,
             const float* __restrict__ wA, const float* __restrict__ wB,
             const float* __restrict__ linm, const float* __restrict__ fd,
             const float* __restrict__ fr, int l) {
    const int lout = l - 12;
    const int tid  = threadIdx.x;          // 0..511
    const int t    = tid & 255;            // position within half
    // wave-uniform half index, forced into SGPR (waves 0-3: half 0, waves 4-7: half 1)
    const int half = __builtin_amdgcn_readfirstlane(tid >> 8);
    const int cob  = half * COH;           // first output channel of this half (SGPR)
    const int t0   = blockIdx.x * TTILE;   // multiple of 6
    const int b    = blockIdx.y;

    // per-half weight/output bases off the SGPR cob -> scalar loads inside B/D
    const float* wAh = wA + cob * CH * 3;
    const float* wBh = wB + cob * CH * 3;

    __shared__ float xs[CH][XS_PAD];       // x tile; after C1+B, reused as gs tile
    __shared__ float lxs[NW][LXS_PAD];     // Legendre coeffs, layout [wl][u], u = m*20+c
    __shared__ float lm_s[CH * MM * MM];   // lin_m[i] : [g][o][i]
    __shared__ float fr_s[MM * NPOLY];     // filt_r

    const float* xb = x + (size_t)b * CH * l;

    for (int i = tid; i < CH * MM * MM; i += 512) lm_s[i] = linm[i];
    for (int i = tid; i < MM * NPOLY; i += 512)   fr_s[i] = fr[i];

    // stage A: load x tile (zero-fill past end; those outputs are masked)
    for (int i = tid; i < CH * XS_LEN; i += 512) {
        int c = i / XS_LEN, p = i - c * XS_LEN;
        int gp = t0 + p;
        xs[c][p] = (gp < l) ? xb[(size_t)c * l + gp] : 0.f;
    }
    __syncthreads();

    // stage C1: Legendre decomposition per (window, channel): Lx[m] = sum_k x[6wl+k]*fd[m][k]/2
    for (int item = tid; item < NW * CH; item += 512) {
        int wl = item / CH, c = item - wl * CH;
        float xv[NPOLY];
#pragma unroll
        for (int k = 0; k < NPOLY; ++k) xv[k] = xs[c][6 * wl + k];
#pragma unroll
        for (int m = 0; m < MM; ++m) {
            float acc = 0.f;
#pragma unroll
            for (int k = 0; k < NPOLY; ++k)
                acc = fmaf(xv[k], fd[m * NPOLY + k], acc);
            lxs[wl][m * CH + c] = acc * 0.5f;
        }
    }

    // stage B: this half computes gelu(conv_a(x)) for its 10 output channels
    float gv[COH];
    if (t < GS_LEN) {
#pragma unroll
        for (int co = 0; co < COH; ++co) gv[co] = 0.f;
#pragma unroll 1
        for (int cig = 0; cig < CH; cig += CCHUNK) {
            float xw[CCHUNK][3];
#pragma unroll
            for (int j = 0; j < CCHUNK; ++j) {
                xw[j][0] = xs[cig + j][t + 4];
                xw[j][1] = xs[cig + j][t + 5];
                xw[j][2] = xs[cig + j][t + 6];
            }
#pragma unroll
            for (int co = 0; co < COH; ++co) {
                float acc = gv[co];
#pragma unroll
                for (int j = 0; j < CCHUNK; ++j)
#pragma unroll
                    for (int k = 0; k < 3; ++k)
                        acc = fmaf(xw[j][k], wAh[(co * CH + cig + j) * 3 + k], acc);
                gv[co] = acc;
            }
        }
#pragma unroll
        for (int co = 0; co < COH; ++co) gv[co] = gelu_exact(gv[co]);
    }
    __syncthreads();   // all reads of xs (C1 + B) complete block-wide

    // write g into the dead xs region (each half writes its 10 rows; cob is SGPR)
    if (t < GS_LEN) {
#pragma unroll
        for (int co = 0; co < COH; ++co) xs[cob + co][t] = gv[co];
    }

    // stage C2: grouped mode mixing on flattened mode-major index u = m*20+c,
    // groups are 6-consecutive u's (block-diagonal -> safe in place)
    for (int item = tid; item < NW * CH; item += 512) {
        int wl = item / CH, g = item - wl * CH;
        float iv[MM], ov[MM];
#pragma unroll
        for (int i = 0; i < MM; ++i) iv[i] = lxs[wl][g * MM + i];
#pragma unroll
        for (int o = 0; o < MM; ++o) {
            float acc = 0.f;
#pragma unroll
            for (int i = 0; i < MM; ++i)
                acc = fmaf(iv[i], lm_s[(g * MM + o) * MM + i], acc);
            ov[o] = acc;
        }
#pragma unroll
        for (int o = 0; o < MM; ++o) lxs[wl][g * MM + o] = ov[o];
    }
    __syncthreads();

    // stage D: out[t'] = gelu( rec[t'+6] + conv_b(g)[t'+4] ) for this half's 10 channels
    if (t < TTILE && t0 + t < lout) {
        const int tp = t;
        float acc[COH];
#pragma unroll
        for (int co = 0; co < COH; ++co) acc[co] = 0.f;
#pragma unroll 1
        for (int cig = 0; cig < CH; cig += CCHUNK) {
            float aw[CCHUNK][3];
#pragma unroll
            for (int j = 0; j < CCHUNK; ++j) {
                aw[j][0] = xs[cig + j][tp];
                aw[j][1] = xs[cig + j][tp + 1];
                aw[j][2] = xs[cig + j][tp + 2];
            }
#pragma unroll
            for (int co = 0; co < COH; ++co) {
                float a = acc[co];
#pragma unroll
                for (int j = 0; j < CCHUNK; ++j)
#pragma unroll
                    for (int k = 0; k < 3; ++k)
                        a = fmaf(aw[j][k], wBh[(co * CH + cig + j) * 3 + k], a);
                acc[co] = a;
            }
        }
        const int r1  = tp % 6;        // (t0+tp+6) % 6
        const int wl1 = tp / 6 + 1;    // local window (t'+6)/6, <= 36 < NW
        float frA[MM], frB[MM];
#pragma unroll
        for (int m = 0; m < MM; ++m) {
            frA[m] = fr_s[m * NPOLY + r1];
            frB[m] = fr_s[m * NPOLY + r1 + 6];
        }
        float* xnb = xn + (size_t)b * CH * lout + (size_t)cob * lout;  // SGPR-uniform base
#pragma unroll
        for (int co = 0; co < COH; ++co) {
            float rec = 0.f;
#pragma unroll
            for (int m = 0; m < MM; ++m) {
                rec = fmaf(lxs[wl1][m * CH + cob + co], frA[m], rec);
                rec = fmaf(lxs[wl1 - 1][m * CH + cob + co], frB[m], rec);
            }
            xnb[(size_t)co * lout + t0 + tp] = gelu_exact(acc[co] + rec);
        }
    }
}

// ---------------- final: gelu(20->128) -> 128->1, slice to 16384 ----------------
__global__ void k_final(const float* __restrict__ x, const float* __restrict__ w11,
                        const float* __restrict__ wout, float* __restrict__ out) {
    int t = blockIdx.x * blockDim.x + threadIdx.x;
    int b = blockIdx.y;
    if (t >= LIN_) return;
    const int l4 = L0 - NB * 12;   // 16386
    const float* xb = x + (size_t)b * CH * l4;
    float xv[CH];
#pragma unroll
    for (int c = 0; c < CH; ++c) xv[c] = xb[(size_t)c * l4 + t];
    float acc0 = 0.f, acc1 = 0.f, acc2 = 0.f, acc3 = 0.f;
    for (int h = 0; h < 128; h += 4) {
        float hv0 = 0.f, hv1 = 0.f, hv2 = 0.f, hv3 = 0.f;
#pragma unroll
        for (int c = 0; c < CH; ++c) {
            hv0 = fmaf(xv[c], w11[(h + 0) * CH + c], hv0);
            hv1 = fmaf(xv[c], w11[(h + 1) * CH + c], hv1);
            hv2 = fmaf(xv[c], w11[(h + 2) * CH + c], hv2);
            hv3 = fmaf(xv[c], w11[(h + 3) * CH + c], hv3);
        }
        acc0 = fmaf(gelu_exact(hv0), wout[h + 0], acc0);
        acc1 = fmaf(gelu_exact(hv1), wout[h + 1], acc1);
        acc2 = fmaf(gelu_exact(hv2), wout[h + 2], acc2);
        acc3 = fmaf(gelu_exact(hv3), wout[h + 3], acc3);
    }
    out[(size_t)b * LIN_ + t] = (acc0 + acc1) + (acc2 + acc3);
}

extern "C" void kernel_launch(void* const* d_in, const int* in_sizes, int n_in,
                              void* d_out, int out_size, void* d_ws, size_t ws_size,
                              hipStream_t stream) {
    const float* input   = (const float*)d_in[0];
    const float* w_first = (const float*)d_in[1];
    const float* conv_a  = (const float*)d_in[2];
    const float* conv_b  = (const float*)d_in[3];
    const float* lin_m   = (const float*)d_in[4];
    const float* w11     = (const float*)d_in[5];
    const float* w_out   = (const float*)d_in[6];
    const float* filt_d  = (const float*)d_in[7];
    const float* filt_r  = (const float*)d_in[8];
    float* out = (float*)d_out;

    const size_t bufElems = (size_t)B_ * CH * L0;   // 10,517,760 floats = 42.07 MB
    float* xA = (float*)d_ws;
    float* xB = xA + bufElems;

    {
        dim3 grid((L0 + 255) / 256, B_);
        k_first<<<grid, 256, 0, stream>>>(input, w_first, xA);
    }

    int l = L0;
    float* cur = xA;
    float* nxt = xB;
    for (int i = 0; i < NB; ++i) {
        int lout  = l - 12;
        int tiles = (lout + TTILE - 1) / TTILE;
        dim3 grid(tiles, B_);
        k_block<<<grid, 512, 0, stream>>>(cur, nxt,
                                          conv_a + i * CH * CH * 3,
                                          conv_b + i * CH * CH * 3,
                                          lin_m + i * CH * MM * MM,
                                          filt_d, filt_r, l);
        float* tswap = cur; cur = nxt; nxt = tswap;
        l = lout;
    }

    {
        dim3 grid((LIN_ + 255) / 256, B_);
        k_final<<<grid, 256, 0, stream>>>(cur, w11, w_out, out);
    }
}